// Round 1
// 574.023 us; speedup vs baseline: 1.0980x; 1.0980x over previous
//
#include <hip/hip_runtime.h>

// Problem constants: B=16384, NE=32, E=128, H=256
constexpr int kB  = 16384;
constexpr int kNE = 32;
constexpr int kE  = 128;
constexpr int kH  = 256;
constexpr int MT  = 64;          // batch rows per block (16 per wave)

typedef __attribute__((ext_vector_type(8))) short short8;
typedef __attribute__((ext_vector_type(4))) float float4v;

__device__ __forceinline__ unsigned short f2bf(float x) {
  unsigned int u = __float_as_uint(x);
  u += 0x7FFFu + ((u >> 16) & 1u);
  return (unsigned short)(u >> 16);
}

// v_cvt_pk_bf16_f32: pack two f32 -> bf16x2 (RNE), single VALU op.
__device__ __forceinline__ unsigned int cvt_pk_bf16(float lo, float hi) {
  unsigned int r;
  asm("v_cvt_pk_bf16_f32 %0, %1, %2" : "=v"(r) : "v"(lo), "v"(hi));
  return r;
}

// tanh-form GELU (|err| vs erf-GELU < ~1e-3, well under loss threshold)
__device__ __forceinline__ float gelu_f(float x) {
  float x2 = x * x;
  float w = x * fmaf(x2, -0.10294428f, -2.30220795f);
  float z = __builtin_amdgcn_exp2f(w);
  return x * __builtin_amdgcn_rcpf(1.0f + z);
}

__device__ __forceinline__ void load_lds16(const unsigned short* g, unsigned short* l) {
  // LDS dest is wave-uniform base; HW places lane i at base + i*16B.
  __builtin_amdgcn_global_load_lds(
      (const __attribute__((address_space(1))) unsigned int*)g,
      (__attribute__((address_space(3))) unsigned int*)l, 16, 0, 0);
}

// ---------------- prep: gather weights into MFMA-fragment order, bf16 ----------------
// Fragment blocks of 1 KB = 64 lanes x 16 B, lane l = q*16+col:
//   W1F[n][c][kt][t ][l][j] = W1[n][k = 32kt+8q+j][h = 64c+16t+col]   (A-frag of h^T = W1^T . feat^T)
//   W2F[n][c][kt][je][l][j] = W2[n][h = 64c+32kt+8q+j][e = 16je+col]  (A-frag of pred^T = W2^T . g^T)
__global__ __launch_bounds__(256)
void prep_weights(const float* __restrict__ W1, const float* __restrict__ W2,
                  unsigned short* __restrict__ W1F, unsigned short* __restrict__ W2F)
{
  const int n    = blockIdx.x;
  const int lane = threadIdx.x & 63;
  const int wv   = threadIdx.x >> 6;
  const int q = lane >> 4, col = lane & 15;
  const int fb = blockIdx.z * 4 + wv;       // 0..63 fragment-block index
  const int c  = fb >> 4;
  if (blockIdx.y == 0) {
    const int kt = (fb >> 2) & 3, t = fb & 3;
    const float* src = W1 + (size_t)n * kE * kH
                          + (size_t)(kt * 32 + q * 8) * kH + (c * 64 + t * 16 + col);
    unsigned short* dst = W1F + (size_t)n * (kH * kE) + ((size_t)fb * 64 + lane) * 8;
    short8 v;
#pragma unroll
    for (int j = 0; j < 8; ++j) v[j] = (short)f2bf(src[(size_t)j * kH]);
    *(short8*)dst = v;
  } else {
    const int kt = (fb >> 3) & 1, je = fb & 7;
    const float* src = W2 + (size_t)n * kH * kE
                          + (size_t)(c * 64 + kt * 32 + q * 8) * kE + (je * 16 + col);
    unsigned short* dst = W2F + (size_t)n * (kE * kH) + ((size_t)fb * 64 + lane) * 8;
    short8 v;
#pragma unroll
    for (int j = 0; j < 8; ++j) v[j] = (short)f2bf(src[(size_t)j * kE]);
    *(short8*)dst = v;
  }
}

// ---------------- main kernel ----------------
// Swapped-operand formulation: m (batch) lives in lanes for BOTH GEMMs, so the
// h-axis is register-local and the GEMM1->GEMM2 transpose is done with
// cvt_pk + permlane{32,16}_swap instead of an LDS round-trip.
__global__ __launch_bounds__(256, 4)
void distill_moe_mse(const float* __restrict__ features,
                     const float* __restrict__ target,
                     const unsigned short* __restrict__ W1F,
                     const float* __restrict__ b1,
                     const unsigned short* __restrict__ W2F,
                     const float* __restrict__ b2,
                     float* __restrict__ out)
{
  __shared__ __align__(16) unsigned short sW1[8192];   // 16 KB fragment-linear chunk
  __shared__ __align__(16) unsigned short sW2[8192];   // 16 KB

  const int tid  = threadIdx.x;
  const int lane = tid & 63;
  const int w    = tid >> 6;       // wave 0..3, owns m-cols 16w..16w+15
  const int q    = lane >> 4;
  const int col  = lane & 15;
  const int n    = blockIdx.y;
  const int m    = blockIdx.x * MT + 16 * w + col;

  // ---- features row -> bf16 B-fragments in registers (no LDS, no barrier) ----
  const float* arow = features + ((size_t)m * kNE + n) * kE;
  short8 areg[4];
#pragma unroll
  for (int kt = 0; kt < 4; ++kt) {
    float4v f0 = *(const float4v*)(arow + kt * 32 + q * 8);
    float4v f1 = *(const float4v*)(arow + kt * 32 + q * 8 + 4);
    union { unsigned int u[4]; short8 s; } pk;
    pk.u[0] = cvt_pk_bf16(f0.x, f0.y);
    pk.u[1] = cvt_pk_bf16(f0.z, f0.w);
    pk.u[2] = cvt_pk_bf16(f1.x, f1.y);
    pk.u[3] = cvt_pk_bf16(f1.z, f1.w);
    areg[kt] = pk.s;
  }

  float4v acc2[8];                 // pred^T: e = 16je + 4q + r, m = col
#pragma unroll
  for (int je = 0; je < 8; ++je) acc2[je] = (float4v){0.f, 0.f, 0.f, 0.f};

  const unsigned short* W1n = W1F + (size_t)n * (kH * kE);
  const unsigned short* W2n = W2F + (size_t)n * (kE * kH);
  const float* b1n = b1 + n * kH;

  for (int c = 0; c < 4; ++c) {
    if (c) __syncthreads();        // all waves done reading previous chunk
    // ---- stage chunk c: 16 KB W1F + 16 KB W2F, linear global_load_lds x16B ----
    {
      const unsigned short* g1 = W1n + c * 8192;
      const unsigned short* g2 = W2n + c * 8192;
#pragma unroll
      for (int i = 0; i < 4; ++i) {
        int seg = i * 4 + w;                     // wave-uniform segment
        load_lds16(g1 + seg * 512 + lane * 8, &sW1[seg * 512]);
        load_lds16(g2 + seg * 512 + lane * 8, &sW2[seg * 512]);
      }
    }
    __syncthreads();               // compiler drains vmcnt(0) before barrier

    // ---- GEMM1 (swapped): h^T[16t+4q+r][m=col] over k=128 ----
    float4v acc1[4];
#pragma unroll
    for (int t = 0; t < 4; ++t) acc1[t] = (float4v){0.f, 0.f, 0.f, 0.f};
#pragma unroll
    for (int kt = 0; kt < 4; ++kt) {
#pragma unroll
      for (int t = 0; t < 4; ++t) {
        short8 wf = *(const short8*)&sW1[(kt * 4 + t) * 512 + lane * 8];  // 64 lanes x 16B contiguous
        acc1[t] = __builtin_amdgcn_mfma_f32_16x16x32_bf16(wf, areg[kt], acc1[t], 0, 0, 0);
      }
    }

    // ---- bias + GELU + pack pairs along h ----
    unsigned int p[4][2];          // p[t][s] = bf16x2 at h = 16t + 4q + 2s (+1)
    const float* bc = b1n + c * 64;
#pragma unroll
    for (int t = 0; t < 4; ++t) {
      float4v bias = *(const float4v*)(bc + t * 16 + q * 4);
      float g0 = gelu_f(acc1[t][0] + bias.x);
      float g1 = gelu_f(acc1[t][1] + bias.y);
      float g2 = gelu_f(acc1[t][2] + bias.z);
      float g3 = gelu_f(acc1[t][3] + bias.w);
      p[t][0] = cvt_pk_bf16(g0, g1);
      p[t][1] = cvt_pk_bf16(g2, g3);
    }

    // ---- in-register transpose: q-group redistribution -> GEMM2 B-frags ----
    // dest lane (q,col), word j2 = pair h = 32k2 + 8q + 2j2, sourced from
    // p[2k2 + (q>>1)][j2&1] of lane group 2(q&1)+(j2>>1):
    // one permlane32_swap then one permlane16_swap delivers exactly this.
    short8 bfrag[2];
#pragma unroll
    for (int k2 = 0; k2 < 2; ++k2) {
      union { unsigned int u[4]; short8 s; } bf;
#pragma unroll
      for (int s = 0; s < 2; ++s) {
        auto uv = __builtin_amdgcn_permlane32_swap(p[2 * k2][s], p[2 * k2 + 1][s], false, false);
        auto mm = __builtin_amdgcn_permlane16_swap((unsigned int)uv[0], (unsigned int)uv[1], false, false);
        bf.u[s]     = (unsigned int)mm[0];   // j2 = s
        bf.u[2 + s] = (unsigned int)mm[1];   // j2 = 2 + s
      }
      bfrag[k2] = bf.s;
    }

    // ---- GEMM2 partial (swapped): pred^T += W2F . g^T over this h-chunk ----
#pragma unroll
    for (int k2 = 0; k2 < 2; ++k2) {
#pragma unroll
      for (int je = 0; je < 8; ++je) {
        short8 wf = *(const short8*)&sW2[(k2 * 8 + je) * 512 + lane * 8];
        acc2[je] = __builtin_amdgcn_mfma_f32_16x16x32_bf16(wf, bfrag[k2], acc2[je], 0, 0, 0);
      }
    }
  }

  // ---- epilogue: +b2, diff vs target, square, reduce, atomicAdd ----
  const float* trow = target + ((size_t)m * kNE + n) * kE;
  const float* b2n  = b2 + n * kE;
  float local = 0.f;
#pragma unroll
  for (int je = 0; je < 8; ++je) {
    float4v tg = *(const float4v*)(trow + je * 16 + q * 4);
    float4v bb = *(const float4v*)(b2n + je * 16 + q * 4);
#pragma unroll
    for (int r = 0; r < 4; ++r) {
      float d = acc2[je][r] + bb[r] - tg[r];
      local += d * d;
    }
  }
#pragma unroll
  for (int off = 32; off > 0; off >>= 1)
    local += __shfl_down(local, off, 64);

  __syncthreads();                          // all waves done with sW1 reads
  float* sRedF = (float*)sW1;               // reuse LDS for the 4-wave reduction
  if (lane == 0) sRedF[w] = local;
  __syncthreads();
  if (tid == 0)
    atomicAdd(out, (sRedF[0] + sRedF[1] + sRedF[2] + sRedF[3]) *
                       (1.0f / ((float)kB * (float)kNE * (float)kE)));
}

extern "C" void kernel_launch(void* const* d_in, const int* in_sizes, int n_in,
                              void* d_out, int out_size, void* d_ws, size_t ws_size,
                              hipStream_t stream) {
  const float* features = (const float*)d_in[0];
  const float* target   = (const float*)d_in[1];
  const float* W1       = (const float*)d_in[2];
  const float* b1       = (const float*)d_in[3];
  const float* W2       = (const float*)d_in[4];
  const float* b2       = (const float*)d_in[5];
  float* out = (float*)d_out;

  unsigned short* W1F = (unsigned short*)d_ws;                 // 2 MB fragment-packed
  unsigned short* W2F = W1F + (size_t)kNE * kH * kE;           // 2 MB

  hipMemsetAsync(out, 0, sizeof(float), stream);

  {
    dim3 grid(kNE, 2, 16);
    prep_weights<<<grid, dim3(256), 0, stream>>>(W1, W2, W1F, W2F);
  }
  {
    dim3 grid(kB / MT, kNE);
    distill_moe_mse<<<grid, dim3(256), 0, stream>>>(features, target, W1F, b1, W2F, b2, out);
  }
}

// Round 2
// 540.769 us; speedup vs baseline: 1.1655x; 1.0615x over previous
//
#include <hip/hip_runtime.h>

// Problem constants: B=16384, NE=32, E=128, H=256
constexpr int kB  = 16384;
constexpr int kNE = 32;
constexpr int kE  = 128;
constexpr int kH  = 256;
constexpr int MT  = 128;      // batch rows per block: 2 m-tiles x 64
constexpr int NCH = 8;        // h-chunks of 32

typedef __attribute__((ext_vector_type(8))) short short8;
typedef __attribute__((ext_vector_type(4))) float float4v;

__device__ __forceinline__ unsigned short f2bf(float x) {
  unsigned int u = __float_as_uint(x);
  u += 0x7FFFu + ((u >> 16) & 1u);
  return (unsigned short)(u >> 16);
}

// v_cvt_pk_bf16_f32: pack two f32 -> bf16x2 (RNE), single VALU op.
__device__ __forceinline__ unsigned int cvt_pk_bf16(float lo, float hi) {
  unsigned int r;
  asm("v_cvt_pk_bf16_f32 %0, %1, %2" : "=v"(r) : "v"(lo), "v"(hi));
  return r;
}

// tanh-form GELU (|err| vs erf-GELU < ~1e-3, well under loss threshold)
__device__ __forceinline__ float gelu_f(float x) {
  float x2 = x * x;
  float w = x * fmaf(x2, -0.10294428f, -2.30220795f);
  float z = __builtin_amdgcn_exp2f(w);
  return x * __builtin_amdgcn_rcpf(1.0f + z);
}

__device__ __forceinline__ void load_lds16(const unsigned short* g, unsigned short* l) {
  // LDS dest is wave-uniform base; HW places lane i at base + i*16B.
  __builtin_amdgcn_global_load_lds(
      (const __attribute__((address_space(1))) unsigned int*)g,
      (__attribute__((address_space(3))) unsigned int*)l, 16, 0, 0);
}

// ---------------- prep: gather weights into MFMA-fragment order (32-h chunks) ----------------
// Fragment blocks of 1 KB = 64 lanes x 16 B, lane l = q*16+col:
//   W1F block g = c*8 + kt*2 + t  (c<8, kt<4, t<2):
//     [l][j] = W1[n][k = 32kt+8q+j][h = 32c+16t+col]
//   W2F block g = c*8 + je        (c<8, je<8):
//     [l][j] = W2[n][h = 32c+8q+j][e = 16je+col]
__global__ __launch_bounds__(256)
void prep_weights(const float* __restrict__ W1, const float* __restrict__ W2,
                  unsigned short* __restrict__ W1F, unsigned short* __restrict__ W2F)
{
  const int n    = blockIdx.x;
  const int lane = threadIdx.x & 63;
  const int wv   = threadIdx.x >> 6;
  const int q = lane >> 4, col = lane & 15;
  const int g = blockIdx.z * 4 + wv;        // 0..63 fragment-block index
  const int c = g >> 3;                     // h-chunk 0..7
  if (blockIdx.y == 0) {
    const int kt = (g >> 1) & 3, t = g & 1;
    const float* src = W1 + (size_t)n * kE * kH
                          + (size_t)(kt * 32 + q * 8) * kH + (c * 32 + t * 16 + col);
    unsigned short* dst = W1F + (size_t)n * (kH * kE) + ((size_t)g * 64 + lane) * 8;
    short8 v;
#pragma unroll
    for (int j = 0; j < 8; ++j) v[j] = (short)f2bf(src[(size_t)j * kH]);
    *(short8*)dst = v;
  } else {
    const int je = g & 7;
    const float* src = W2 + (size_t)n * kH * kE
                          + (size_t)(c * 32 + q * 8) * kE + (je * 16 + col);
    unsigned short* dst = W2F + (size_t)n * (kE * kH) + ((size_t)g * 64 + lane) * 8;
    short8 v;
#pragma unroll
    for (int j = 0; j < 8; ++j) v[j] = (short)f2bf(src[(size_t)j * kE]);
    *(short8*)dst = v;
  }
}

// ---------------- main kernel ----------------
// Swapped-operand GEMMs (m in lanes), 2 m-tiles/block sharing staged weights,
// double-buffered weight staging with counted vmcnt (never drained to 0 in-loop),
// raw s_barrier. No VMEM ops inside the compute phase (bias comes from LDS),
// so the inline-asm vmcnt accounting is exact.
__global__ __launch_bounds__(256, 3)
void distill_moe_mse(const float* __restrict__ features,
                     const float* __restrict__ target,
                     const unsigned short* __restrict__ W1F,
                     const float* __restrict__ b1,
                     const unsigned short* __restrict__ W2F,
                     const float* __restrict__ b2,
                     float* __restrict__ out)
{
  __shared__ __align__(16) unsigned short sW[2][8192];  // [buf][W1:0..4095 | W2:4096..8191]
  __shared__ __align__(16) float sB1[kH];
  __shared__ float sRed[4];

  const int tid  = threadIdx.x;
  const int lane = tid & 63;
  const int w    = tid >> 6;       // wave 0..3
  const int q    = lane >> 4;
  const int col  = lane & 15;

  // bijective XCD swizzle: 4096 blocks -> 512 consecutive per XCD -> 4 experts/XCD
  const int bid = blockIdx.y * gridDim.x + blockIdx.x;
  const int swz = (bid & 7) * (kNE * (kB / MT) / 8) + (bid >> 3);
  const int n   = swz >> 7;        // expert
  const int b0  = (swz & 127) * MT;
  const int m0  = b0 + 16 * w + col;

  const unsigned short* W1n = W1F + (size_t)n * (kH * kE);
  const unsigned short* W2n = W2F + (size_t)n * (kE * kH);
  const float* b1n = b1 + n * kH;
  const float* b2n = b2 + n * kE;

  // ---- features (2 m-tiles) -> bf16 B-fragments in registers ----
  short8 areg[2][4];
#pragma unroll
  for (int mt = 0; mt < 2; ++mt) {
    const float* arow = features + ((size_t)(m0 + mt * 64) * kNE + n) * kE;
#pragma unroll
    for (int kt = 0; kt < 4; ++kt) {
      float4v f0 = *(const float4v*)(arow + kt * 32 + q * 8);
      float4v f1 = *(const float4v*)(arow + kt * 32 + q * 8 + 4);
      union { unsigned int u[4]; short8 s; } pk;
      pk.u[0] = cvt_pk_bf16(f0.x, f0.y);
      pk.u[1] = cvt_pk_bf16(f0.z, f0.w);
      pk.u[2] = cvt_pk_bf16(f1.x, f1.y);
      pk.u[3] = cvt_pk_bf16(f1.z, f1.w);
      areg[mt][kt] = pk.s;
    }
  }

  // ---- b1 -> LDS (so in-loop bias reads are ds_read, not VMEM) ----
  if (tid < 64) {
    float4v bv = *(const float4v*)(b1n + tid * 4);
    *(float4v*)&sB1[tid * 4] = bv;
  }

  float4v acc2[2][8];              // pred^T: e = 16je + 4q + r, m = col
#pragma unroll
  for (int mt = 0; mt < 2; ++mt)
#pragma unroll
    for (int je = 0; je < 8; ++je) acc2[mt][je] = (float4v){0.f, 0.f, 0.f, 0.f};

  // full drain (vmcnt(0) lgkmcnt(0)) + barrier: clean slate for manual vmcnt counting
  __syncthreads();

  // ---- stage helper: one 16 KB chunk (8 KB W1 + 8 KB W2), 4 loads/thread ----
  auto stage = [&](int buf, int c) {
    const unsigned short* g1 = W1n + c * 4096;
    const unsigned short* g2 = W2n + c * 4096;
#pragma unroll
    for (int i = 0; i < 2; ++i) {
      int s = i * 4 + w;                       // wave-uniform segment 0..7
      load_lds16(g1 + s * 512 + lane * 8, &sW[buf][s * 512]);
      load_lds16(g2 + s * 512 + lane * 8, &sW[buf][4096 + s * 512]);
    }
  };

  // prologue: two chunks in flight (8 outstanding loads/thread)
  stage(0, 0);
  stage(1, 1);

#pragma unroll
  for (int c = 0; c < NCH; ++c) {
    // wait for chunk c's 4 loads; keep chunk c+1's 4 in flight
    if (c < NCH - 1) asm volatile("s_waitcnt vmcnt(4)" ::: "memory");
    else             asm volatile("s_waitcnt vmcnt(0)" ::: "memory");
    __builtin_amdgcn_sched_barrier(0);
    __builtin_amdgcn_s_barrier();
    __builtin_amdgcn_sched_barrier(0);

    const unsigned short* w1c = &sW[c & 1][0];
    const unsigned short* w2c = &sW[c & 1][4096];

    // ---- GEMM1: h_local = 16t+4q+r, m = col; K = 128 ----
    float4v acc1[2][2];
#pragma unroll
    for (int mt = 0; mt < 2; ++mt)
#pragma unroll
      for (int t = 0; t < 2; ++t) acc1[mt][t] = (float4v){0.f, 0.f, 0.f, 0.f};

    __builtin_amdgcn_s_setprio(1);
#pragma unroll
    for (int kt = 0; kt < 4; ++kt) {
#pragma unroll
      for (int t = 0; t < 2; ++t) {
        short8 wf = *(const short8*)&w1c[(kt * 2 + t) * 512 + lane * 8];
#pragma unroll
        for (int mt = 0; mt < 2; ++mt)
          acc1[mt][t] = __builtin_amdgcn_mfma_f32_16x16x32_bf16(wf, areg[mt][kt], acc1[mt][t], 0, 0, 0);
      }
    }
    __builtin_amdgcn_s_setprio(0);

    // ---- bias + GELU + pack + in-register transpose -> GEMM2 B-frags ----
    short8 bfrag[2];
#pragma unroll
    for (int mt = 0; mt < 2; ++mt) {
      unsigned int p[2][2];
#pragma unroll
      for (int t = 0; t < 2; ++t) {
        float4v bias = *(const float4v*)&sB1[c * 32 + t * 16 + q * 4];
        float g0 = gelu_f(acc1[mt][t][0] + bias.x);
        float g1 = gelu_f(acc1[mt][t][1] + bias.y);
        float g2 = gelu_f(acc1[mt][t][2] + bias.z);
        float g3 = gelu_f(acc1[mt][t][3] + bias.w);
        p[t][0] = cvt_pk_bf16(g0, g1);
        p[t][1] = cvt_pk_bf16(g2, g3);
      }
      union { unsigned int u[4]; short8 s; } bf;
#pragma unroll
      for (int s2 = 0; s2 < 2; ++s2) {
        auto uv = __builtin_amdgcn_permlane32_swap(p[0][s2], p[1][s2], false, false);
        auto mm = __builtin_amdgcn_permlane16_swap((unsigned int)uv[0], (unsigned int)uv[1], false, false);
        bf.u[s2]     = (unsigned int)mm[0];
        bf.u[2 + s2] = (unsigned int)mm[1];
      }
      bfrag[mt] = bf.s;
    }

    // ---- GEMM2 partial: this 32-h chunk is one MFMA K-step ----
    __builtin_amdgcn_s_setprio(1);
#pragma unroll
    for (int je = 0; je < 8; ++je) {
      short8 wf = *(const short8*)&w2c[je * 512 + lane * 8];
#pragma unroll
      for (int mt = 0; mt < 2; ++mt)
        acc2[mt][je] = __builtin_amdgcn_mfma_f32_16x16x32_bf16(wf, bfrag[mt], acc2[mt][je], 0, 0, 0);
    }
    __builtin_amdgcn_s_setprio(0);

    // all LDS reads of this buffer done -> safe to restage it after the barrier
    asm volatile("s_waitcnt lgkmcnt(0)" ::: "memory");
    __builtin_amdgcn_sched_barrier(0);
    __builtin_amdgcn_s_barrier();
    __builtin_amdgcn_sched_barrier(0);
    if (c + 2 < NCH) stage(c & 1, c + 2);
  }

  // ---- epilogue: +b2, diff vs target, square, reduce, atomicAdd ----
  float local = 0.f;
#pragma unroll
  for (int je = 0; je < 8; ++je) {
    float4v bb = *(const float4v*)(b2n + je * 16 + q * 4);
#pragma unroll
    for (int mt = 0; mt < 2; ++mt) {
      const float* trow = target + ((size_t)(m0 + mt * 64) * kNE + n) * kE;
      float4v tg = *(const float4v*)(trow + je * 16 + q * 4);
#pragma unroll
      for (int r = 0; r < 4; ++r) {
        float d = acc2[mt][je][r] + bb[r] - tg[r];
        local += d * d;
      }
    }
  }
#pragma unroll
  for (int off = 32; off > 0; off >>= 1)
    local += __shfl_down(local, off, 64);

  if (lane == 0) sRed[w] = local;
  __syncthreads();
  if (tid == 0)
    atomicAdd(out, (sRed[0] + sRed[1] + sRed[2] + sRed[3]) *
                       (1.0f / ((float)kB * (float)kNE * (float)kE)));
}

extern "C" void kernel_launch(void* const* d_in, const int* in_sizes, int n_in,
                              void* d_out, int out_size, void* d_ws, size_t ws_size,
                              hipStream_t stream) {
  const float* features = (const float*)d_in[0];
  const float* target   = (const float*)d_in[1];
  const float* W1       = (const float*)d_in[2];
  const float* b1       = (const float*)d_in[3];
  const float* W2       = (const float*)d_in[4];
  const float* b2       = (const float*)d_in[5];
  float* out = (float*)d_out;

  unsigned short* W1F = (unsigned short*)d_ws;                 // 2 MB fragment-packed
  unsigned short* W2F = W1F + (size_t)kNE * kH * kE;           // 2 MB

  hipMemsetAsync(out, 0, sizeof(float), stream);

  {
    dim3 grid(kNE, 2, 16);
    prep_weights<<<grid, dim3(256), 0, stream>>>(W1, W2, W1F, W2F);
  }
  {
    dim3 grid(kB / MT, kNE);
    distill_moe_mse<<<grid, dim3(256), 0, stream>>>(features, target, W1F, b1, W2F, b2, out);
  }
}